// Round 5
// baseline (986.747 us; speedup 1.0000x reference)
//
#include <hip/hip_runtime.h>
#include <hip/hip_bf16.h>

#define D 768
#define BM 64
#define NCHM 12          // K-chunks per model (768/64)
#define NTAB 512         // ND
#define NS 64
#define NGK 24           // kc granules per row (768/32)
#define NGN 48           // n-groups (768/16)

typedef short short8v __attribute__((ext_vector_type(8)));
typedef short short4v __attribute__((ext_vector_type(4)));
typedef float f32x4 __attribute__((ext_vector_type(4)));

static __device__ __forceinline__ short8v cvt8(float4 a, float4 b) {
    union { short8v v; __hip_bfloat162 h[4]; } u;
    u.h[0] = __float22bfloat162_rn({a.x, a.y});
    u.h[1] = __float22bfloat162_rn({a.z, a.w});
    u.h[2] = __float22bfloat162_rn({b.x, b.y});
    u.h[3] = __float22bfloat162_rn({b.z, b.w});
    return u.v;
}

static __device__ __forceinline__ short4v cvt4(float4 a) {
    union { short4v v; __hip_bfloat162 h[2]; } u;
    u.h[0] = __float22bfloat162_rn({a.x, a.y});
    u.h[1] = __float22bfloat162_rn({a.z, a.w});
    return u.v;
}

static __device__ __forceinline__ float fast_tanh(float x) {
    float e = __expf(2.0f * x);
    return 1.0f - 2.0f * __builtin_amdgcn_rcpf(e + 1.0f);
}

static __device__ __forceinline__ float dot4(float4 a, float4 b) {
    return a.x * b.x + a.y * b.y + a.z * b.z + a.w * b.w;
}

// ---------------- pairs scan: mark live table rows ----------------
__global__ void k_scan_pairs(const int* __restrict__ pairs, int* __restrict__ flags, int B) {
    int i = blockIdx.x * blockDim.x + threadIdx.x;
    if (i < B) {
        int idx = pairs[(size_t)i * 3];
        if (idx >= 0 && idx < NTAB) atomicOr(&flags[idx], 1);
    }
}

// ---- fused: gather tables (bid < NTAB*4) + W fp32->bf16 fragment pack (rest) ----
// Wq layout: [model][G=g/3][kc][j=g%3][lane][8]  (wave's 3 n-groups contiguous per kc)
__global__ void k_tables_convq(const float* __restrict__ db, const float* __restrict__ da,
                               const float* __restrict__ W1b, const float* __restrict__ W2b,
                               const float* __restrict__ W1a, const float* __restrict__ W2a,
                               const int* __restrict__ flags,
                               float* __restrict__ T1b, float* __restrict__ T2b, float* __restrict__ Ta,
                               const float* __restrict__ wb_f, const float* __restrict__ wa_f,
                               unsigned short* __restrict__ Wq) {
    int bid = blockIdx.x;
    if (bid >= NTAB * 4) {
        int widx = (bid - NTAB * 4) * 4 + (threadIdx.x >> 6);
        if (widx >= 2 * NGN * NGK) return;
        int model = widx / (NGN * NGK);
        int rem = widx % (NGN * NGK);
        int g = rem / NGK;
        int kc = rem % NGK;
        int l = threadIdx.x & 63;
        const float* Wsrc = model ? wa_f : wb_f;
        const float* src = Wsrc + (size_t)(g * 16 + (l & 15)) * D + kc * 32 + (l >> 4) * 8;
        float4 f0 = *(const float4*)src;
        float4 f1 = *(const float4*)(src + 4);
        size_t o = ((((size_t)(model * 16 + g / 3) * NGK + kc) * 3) + (g % 3)) * 512 + l * 8;
        *(short8v*)(Wq + o) = cvt8(f0, f1);
        return;
    }
    int d = bid >> 2;
    int q = bid & 3;
    if (!flags[d]) return;
    int lane = threadIdx.x & 63;
    int wid = threadIdx.x >> 6;                         // 0..3

    float4 a0[3], a1[3], b0[3], b1[3], c0[3], c1[3];
    #pragma unroll
    for (int i = 0; i < 3; ++i) {
        a0[i] = ((const float4*)W1b)[lane + 64 * i];
        a1[i] = ((const float4*)(W1b + D))[lane + 64 * i];
        b0[i] = ((const float4*)W2b)[lane + 64 * i];
        b1[i] = ((const float4*)(W2b + D))[lane + 64 * i];
        float4 p = ((const float4*)W1a)[lane + 64 * i];
        float4 qv = ((const float4*)W2a)[lane + 64 * i];
        c0[i] = make_float4(p.x + qv.x, p.y + qv.y, p.z + qv.z, p.w + qv.w);
        p = ((const float4*)(W1a + D))[lane + 64 * i];
        qv = ((const float4*)(W2a + D))[lane + 64 * i];
        c1[i] = make_float4(p.x + qv.x, p.y + qv.y, p.z + qv.z, p.w + qv.w);
    }

    #pragma unroll
    for (int si = 0; si < 4; ++si) {
        int s = q * 16 + wid + si * 4;
        size_t roff = ((size_t)d * NS + s) * D;
        const float4* rb = (const float4*)(db + roff);
        const float4* ra = (const float4*)(da + roff);
        float sa0 = 0, sa1 = 0, sb0 = 0, sb1 = 0, sc0 = 0, sc1 = 0;
        #pragma unroll
        for (int i = 0; i < 3; ++i) {
            float4 xb = rb[lane + 64 * i];
            float4 xa = ra[lane + 64 * i];
            sa0 += dot4(xb, a0[i]); sa1 += dot4(xb, a1[i]);
            sb0 += dot4(xb, b0[i]); sb1 += dot4(xb, b1[i]);
            sc0 += dot4(xa, c0[i]); sc1 += dot4(xa, c1[i]);
        }
        #pragma unroll
        for (int off = 32; off; off >>= 1) {
            sa0 += __shfl_xor(sa0, off); sa1 += __shfl_xor(sa1, off);
            sb0 += __shfl_xor(sb0, off); sb1 += __shfl_xor(sb1, off);
            sc0 += __shfl_xor(sc0, off); sc1 += __shfl_xor(sc1, off);
        }
        if (lane == 0) {
            size_t o = ((size_t)d * NS + s) * 2;
            T1b[o] = sa0; T1b[o + 1] = sa1;
            T2b[o] = sb0; T2b[o + 1] = sb1;
            Ta[o]  = sc0; Ta[o + 1]  = sc1;
        }
    }
}

// ---------------- main: reg-staged fp32->bf16, bf16 LDS dbuf, fused tanh+proj ----------------
__global__ __launch_bounds__(512, 6)
void k_main(const float* __restrict__ xbert, const float* __restrict__ xalb,
            const unsigned short* __restrict__ Wq,
            const float* __restrict__ bdb, const float* __restrict__ bda,
            const float* __restrict__ wpb, const float* __restrict__ wpa,
            float* __restrict__ pws, int Brows) {
    __shared__ __align__(16) short xsb[2][BM * 64];      // 2 x 8 KB bf16 chunks (row-XOR swizzled)
    __shared__ float outp[8][BM][2];                     // 4 KB

    const int tid = threadIdx.x;
    const int lane = tid & 63;
    const int wid = tid >> 6;                            // 0..7
    const int l15 = lane & 15;
    const int lhi = lane >> 4;                           // 0..3
    const int xorv = (l15 & 7) << 4;                     // A-frag read swizzle

    const int bid = blockIdx.x;
    const int nh = (bid >> 3) & 1;
    const int mtile = (bid & 7) | ((bid >> 4) << 3);

    // staging: thread -> rows (tid>>4) and +32, float cols (tid&15)*4..+4
    const int srow = tid >> 4;                           // 0..31
    const size_t rowoff1 = ((size_t)mtile * BM + srow) * D + (tid & 15) * 4;
    const size_t rowoff2 = rowoff1 + (size_t)32 * D;

    // cvt write offsets (swizzled bf16)
    const int cc2 = (tid & 15) * 8;
    const int cvw0 = srow * 128 + (cc2 ^ ((srow & 7) << 4));
    const int cvw1 = (srow + 32) * 128 + (cc2 ^ ((srow & 7) << 4));

    float outv = 0.0f;
    f32x4 acc[4][3];
    #pragma unroll
    for (int mi = 0; mi < 4; ++mi)
        #pragma unroll
        for (int ni = 0; ni < 3; ++ni)
            acc[mi][ni] = (f32x4){0.f, 0.f, 0.f, 0.f};

    float4 rA0, rB0, rA1, rB1;

    #define ISSUE(tgt, RA, RB) do {                                          \
        const float* xg_ = ((tgt) < NCHM) ? xbert : xalb;                    \
        const int lc_ = ((tgt) < NCHM) ? (tgt) : (tgt) - NCHM;               \
        RA = *(const float4*)(xg_ + rowoff1 + lc_ * 64);                     \
        RB = *(const float4*)(xg_ + rowoff2 + lc_ * 64);                     \
    } while (0)

    #define CVTW(RA, RB, dbuf) do {                                          \
        *(short4v*)((char*)&xsb[dbuf][0] + cvw0) = cvt4(RA);                 \
        *(short4v*)((char*)&xsb[dbuf][0] + cvw1) = cvt4(RB);                 \
    } while (0)

    #define MFMA_CHUNK(cb) do {                                              \
        const char* xbase_ = (const char*)&xsb[cb][0];                       \
        __builtin_amdgcn_s_setprio(1);                                       \
        _Pragma("unroll")                                                    \
        for (int klo = 0; klo < 2; ++klo) {                                  \
            short8v bv[3];                                                   \
            _Pragma("unroll")                                                \
            for (int ni = 0; ni < 3; ++ni)                                   \
                bv[ni] = *(const short8v*)(wqp + (klo * 3 + ni) * 512);      \
            _Pragma("unroll")                                                \
            for (int mi = 0; mi < 4; ++mi) {                                 \
                short8v av = *(const short8v*)(xbase_ + (mi * 16 + l15) * 128 \
                                 + ((klo * 64 + lhi * 16) ^ xorv));          \
                _Pragma("unroll")                                            \
                for (int ni = 0; ni < 3; ++ni)                               \
                    acc[mi][ni] = __builtin_amdgcn_mfma_f32_16x16x32_bf16(av, bv[ni], acc[mi][ni], 0, 0, 0); \
            }                                                                \
        }                                                                    \
        __builtin_amdgcn_s_setprio(0);                                       \
        wqp += 3072;                                                         \
    } while (0)

    #define EPILOGUE(mm) do {                                                \
        const float* bd_ = (mm) ? bda : bdb;                                 \
        const float* wp_ = (mm) ? wpa : wpb;                                 \
        float bdv[3], w0v[3], w1v[3];                                        \
        _Pragma("unroll")                                                    \
        for (int ni = 0; ni < 3; ++ni) {                                     \
            int n = nh * 384 + wid * 48 + ni * 16 + l15;                     \
            bdv[ni] = bd_[n]; w0v[ni] = wp_[n]; w1v[ni] = wp_[D + n];        \
        }                                                                    \
        float ps[4][4][2] = {};                                              \
        _Pragma("unroll")                                                    \
        for (int mi = 0; mi < 4; ++mi)                                       \
            _Pragma("unroll")                                                \
            for (int ni = 0; ni < 3; ++ni)                                   \
                _Pragma("unroll")                                            \
                for (int r = 0; r < 4; ++r) {                                \
                    float t = fast_tanh(acc[mi][ni][r] + bdv[ni]);           \
                    ps[mi][r][0] += t * w0v[ni];                             \
                    ps[mi][r][1] += t * w1v[ni];                             \
                }                                                            \
        _Pragma("unroll")                                                    \
        for (int mi = 0; mi < 4; ++mi)                                       \
            _Pragma("unroll")                                                \
            for (int r = 0; r < 4; ++r)                                      \
                _Pragma("unroll")                                            \
                for (int cc = 0; cc < 2; ++cc) {                             \
                    float v = ps[mi][r][cc];                                 \
                    v += __shfl_xor(v, 1); v += __shfl_xor(v, 2);            \
                    v += __shfl_xor(v, 4); v += __shfl_xor(v, 8);            \
                    ps[mi][r][cc] = v;                                       \
                }                                                            \
        if (l15 == 0) {                                                      \
            _Pragma("unroll")                                                \
            for (int mi = 0; mi < 4; ++mi)                                   \
                _Pragma("unroll")                                            \
                for (int r = 0; r < 4; ++r) {                                \
                    int row = mi * 16 + lhi * 4 + r;                         \
                    outp[wid][row][0] = ps[mi][r][0];                        \
                    outp[wid][row][1] = ps[mi][r][1];                        \
                }                                                            \
        }                                                                    \
        __syncthreads();                                                     \
        if (tid < 128) {                                                     \
            int row = tid >> 1, cc = tid & 1;                                \
            float s = 0.0f;                                                  \
            _Pragma("unroll")                                                \
            for (int w = 0; w < 8; ++w) s += outp[w][row][cc];               \
            outv += s;                                                       \
        }                                                                    \
        _Pragma("unroll")                                                    \
        for (int mi = 0; mi < 4; ++mi)                                       \
            _Pragma("unroll")                                                \
            for (int ni = 0; ni < 3; ++ni)                                   \
                acc[mi][ni] = (f32x4){0.f, 0.f, 0.f, 0.f};                   \
    } while (0)

    // ---- prologue: chunks 0 and 1 into regs; chunk 0 -> xsb[0] ----
    ISSUE(0, rA0, rB0);
    ISSUE(1, rA1, rB1);
    CVTW(rA0, rB0, 0);
    __syncthreads();

    #pragma unroll 1
    for (int m = 0; m < 2; ++m) {
        const unsigned short* wqp = Wq + ((size_t)(m * 16 + nh * 8 + wid) * NGK * 3) * 512 + lane * 8;
        #pragma unroll 1
        for (int lc = 0; lc < NCHM; lc += 2) {
            const int g = m * NCHM + lc;
            // ---- even chunk (cb = 0) ----
            MFMA_CHUNK(0);
            if (g + 2 < 2 * NCHM) ISSUE(g + 2, rA0, rB0);
            CVTW(rA1, rB1, 1);                            // chunk g+1 -> xsb[1]
            __syncthreads();
            // ---- odd chunk (cb = 1) ----
            MFMA_CHUNK(1);
            if (g + 3 < 2 * NCHM) ISSUE(g + 3, rA1, rB1);
            if (g + 2 < 2 * NCHM) CVTW(rA0, rB0, 0);      // chunk g+2 -> xsb[0]
            if (lc == NCHM - 2) { EPILOGUE(m); } else { __syncthreads(); }
        }
    }
    #undef ISSUE
    #undef CVTW
    #undef MFMA_CHUNK
    #undef EPILOGUE

    // ---- write this block's partial (per n-half) ----
    if (tid < 128) {
        int row = tid >> 1, cc = tid & 1;
        size_t R = (size_t)mtile * BM + row;
        pws[((size_t)nh * Brows + R) * 2 + cc] = outv;
    }
}

// ---------------- combine: n-half partials + gather + biases ----------------
__global__ void k_combine(const float* __restrict__ pws, const int* __restrict__ pairs,
                          const float* __restrict__ T1b, const float* __restrict__ T2b,
                          const float* __restrict__ Ta,
                          const float* __restrict__ bpb, const float* __restrict__ bpa,
                          const float* __restrict__ b1b, const float* __restrict__ b2b,
                          const float* __restrict__ b1a, const float* __restrict__ b2a,
                          float* __restrict__ out, int B) {
    int r = blockIdx.x * blockDim.x + threadIdx.x;
    if (r >= B) return;
    const int* pr = pairs + (size_t)r * 3;
    int i0 = pr[0], j = pr[1], k2 = pr[2];
    #pragma unroll
    for (int c = 0; c < 2; ++c) {
        float g = T1b[((size_t)i0 * NS + j) * 2 + c]
                + T2b[((size_t)i0 * NS + k2) * 2 + c]
                + Ta[((size_t)i0 * NS + j) * 2 + c];
        float bias = bpb[c] + bpa[c] + b1b[c] + b2b[c] + b1a[c] + b2a[c];
        out[(size_t)r * 2 + c] = pws[(size_t)r * 2 + c] + pws[((size_t)B + r) * 2 + c] + g + bias;
    }
}

extern "C" void kernel_launch(void* const* d_in, const int* in_sizes, int n_in,
                              void* d_out, int out_size, void* d_ws, size_t ws_size,
                              hipStream_t stream) {
    const float* xb   = (const float*)d_in[0];
    const float* db   = (const float*)d_in[1];
    const int*   pairs= (const int*)d_in[2];
    const float* xa   = (const float*)d_in[3];
    const float* da   = (const float*)d_in[4];
    const float* Wdb  = (const float*)d_in[5];
    const float* bdb  = (const float*)d_in[6];
    const float* Wda  = (const float*)d_in[7];
    const float* bda  = (const float*)d_in[8];
    const float* Wpb  = (const float*)d_in[9];
    const float* bpb  = (const float*)d_in[10];
    const float* Wpa  = (const float*)d_in[11];
    const float* bpa  = (const float*)d_in[12];
    const float* W1b  = (const float*)d_in[13];
    const float* b1b  = (const float*)d_in[14];
    const float* W2b  = (const float*)d_in[15];
    const float* b2b  = (const float*)d_in[16];
    const float* W1a  = (const float*)d_in[17];
    const float* b1a  = (const float*)d_in[18];
    const float* W2a  = (const float*)d_in[19];
    const float* b2a  = (const float*)d_in[20];
    float* out = (float*)d_out;

    const int B = in_sizes[0] / D;                       // 65536

    char* ws = (char*)d_ws;
    int* flags = (int*)ws;                               // 2048 B
    unsigned short* Wq = (unsigned short*)(ws + 2048);   // 2,359,296 B
    float* T1b = (float*)(ws + 2048 + 2359296);
    float* T2b = T1b + NTAB * NS * 2;
    float* Ta  = T2b + NTAB * NS * 2;
    float* pws = Ta + NTAB * NS * 2;                     // 2*B*2 floats

    hipMemsetAsync(flags, 0, NTAB * sizeof(int), stream);
    k_scan_pairs<<<(B + 255) / 256, 256, 0, stream>>>(pairs, flags, B);
    const int conv_blocks = (2 * NGN * NGK + 3) / 4;     // 576
    k_tables_convq<<<NTAB * 4 + conv_blocks, 256, 0, stream>>>(
        db, da, W1b, W2b, W1a, W2a, flags, T1b, T2b, Ta, Wdb, Wda, Wq);
    k_main<<<(B / BM) * 2, 512, 0, stream>>>(xb, xa, Wq, bdb, bda, Wpb, Wpa, pws, B);
    k_combine<<<(B + 255) / 256, 256, 0, stream>>>(pws, pairs, T1b, T2b, Ta,
                                                   bpb, bpa, b1b, b2b, b1a, b2a, out, B);
}

// Round 6
// 804.265 us; speedup vs baseline: 1.2269x; 1.2269x over previous
//
#include <hip/hip_runtime.h>
#include <hip/hip_bf16.h>

#define D 768
#define BM 64
#define NCHM 12          // K-chunks per model (768/64)
#define NTAB 512         // ND
#define NS 64
#define NGK 24           // kc granules per row (768/32)
#define NGN 48           // n-groups (768/16)

typedef short short8v __attribute__((ext_vector_type(8)));
typedef short short4v __attribute__((ext_vector_type(4)));
typedef float f32x4 __attribute__((ext_vector_type(4)));

static __device__ __forceinline__ short8v cvt8(float4 a, float4 b) {
    union { short8v v; __hip_bfloat162 h[4]; } u;
    u.h[0] = __float22bfloat162_rn({a.x, a.y});
    u.h[1] = __float22bfloat162_rn({a.z, a.w});
    u.h[2] = __float22bfloat162_rn({b.x, b.y});
    u.h[3] = __float22bfloat162_rn({b.z, b.w});
    return u.v;
}

static __device__ __forceinline__ short4v cvt4(float4 a) {
    union { short4v v; __hip_bfloat162 h[2]; } u;
    u.h[0] = __float22bfloat162_rn({a.x, a.y});
    u.h[1] = __float22bfloat162_rn({a.z, a.w});
    return u.v;
}

static __device__ __forceinline__ float fast_tanh(float x) {
    float e = __expf(2.0f * x);
    return 1.0f - 2.0f * __builtin_amdgcn_rcpf(e + 1.0f);
}

static __device__ __forceinline__ float dot4(float4 a, float4 b) {
    return a.x * b.x + a.y * b.y + a.z * b.z + a.w * b.w;
}

// ---------------- pairs scan: mark live table rows ----------------
__global__ void k_scan_pairs(const int* __restrict__ pairs, int* __restrict__ flags, int B) {
    int i = blockIdx.x * blockDim.x + threadIdx.x;
    if (i < B) {
        int idx = pairs[(size_t)i * 3];
        if (idx >= 0 && idx < NTAB) atomicOr(&flags[idx], 1);
    }
}

// ---- fused: gather tables (bid < NTAB*4) + W fp32->bf16 fragment pack (rest) ----
// Wq layout: [model][G=g/3][kc][j=g%3][lane][8]  (48-col block G contiguous per kc)
__global__ void k_tables_convq(const float* __restrict__ db, const float* __restrict__ da,
                               const float* __restrict__ W1b, const float* __restrict__ W2b,
                               const float* __restrict__ W1a, const float* __restrict__ W2a,
                               const int* __restrict__ flags,
                               float* __restrict__ T1b, float* __restrict__ T2b, float* __restrict__ Ta,
                               const float* __restrict__ wb_f, const float* __restrict__ wa_f,
                               unsigned short* __restrict__ Wq) {
    int bid = blockIdx.x;
    if (bid >= NTAB * 4) {
        int widx = (bid - NTAB * 4) * 4 + (threadIdx.x >> 6);
        if (widx >= 2 * NGN * NGK) return;
        int model = widx / (NGN * NGK);
        int rem = widx % (NGN * NGK);
        int g = rem / NGK;
        int kc = rem % NGK;
        int l = threadIdx.x & 63;
        const float* Wsrc = model ? wa_f : wb_f;
        const float* src = Wsrc + (size_t)(g * 16 + (l & 15)) * D + kc * 32 + (l >> 4) * 8;
        float4 f0 = *(const float4*)src;
        float4 f1 = *(const float4*)(src + 4);
        size_t o = ((((size_t)(model * 16 + g / 3) * NGK + kc) * 3) + (g % 3)) * 512 + l * 8;
        *(short8v*)(Wq + o) = cvt8(f0, f1);
        return;
    }
    int d = bid >> 2;
    int q = bid & 3;
    if (!flags[d]) return;
    int lane = threadIdx.x & 63;
    int wid = threadIdx.x >> 6;                         // 0..3

    float4 a0[3], a1[3], b0[3], b1[3], c0[3], c1[3];
    #pragma unroll
    for (int i = 0; i < 3; ++i) {
        a0[i] = ((const float4*)W1b)[lane + 64 * i];
        a1[i] = ((const float4*)(W1b + D))[lane + 64 * i];
        b0[i] = ((const float4*)W2b)[lane + 64 * i];
        b1[i] = ((const float4*)(W2b + D))[lane + 64 * i];
        float4 p = ((const float4*)W1a)[lane + 64 * i];
        float4 qv = ((const float4*)W2a)[lane + 64 * i];
        c0[i] = make_float4(p.x + qv.x, p.y + qv.y, p.z + qv.z, p.w + qv.w);
        p = ((const float4*)(W1a + D))[lane + 64 * i];
        qv = ((const float4*)(W2a + D))[lane + 64 * i];
        c1[i] = make_float4(p.x + qv.x, p.y + qv.y, p.z + qv.z, p.w + qv.w);
    }

    #pragma unroll
    for (int si = 0; si < 4; ++si) {
        int s = q * 16 + wid + si * 4;
        size_t roff = ((size_t)d * NS + s) * D;
        const float4* rb = (const float4*)(db + roff);
        const float4* ra = (const float4*)(da + roff);
        float sa0 = 0, sa1 = 0, sb0 = 0, sb1 = 0, sc0 = 0, sc1 = 0;
        #pragma unroll
        for (int i = 0; i < 3; ++i) {
            float4 xb = rb[lane + 64 * i];
            float4 xa = ra[lane + 64 * i];
            sa0 += dot4(xb, a0[i]); sa1 += dot4(xb, a1[i]);
            sb0 += dot4(xb, b0[i]); sb1 += dot4(xb, b1[i]);
            sc0 += dot4(xa, c0[i]); sc1 += dot4(xa, c1[i]);
        }
        #pragma unroll
        for (int off = 32; off; off >>= 1) {
            sa0 += __shfl_xor(sa0, off); sa1 += __shfl_xor(sa1, off);
            sb0 += __shfl_xor(sb0, off); sb1 += __shfl_xor(sb1, off);
            sc0 += __shfl_xor(sc0, off); sc1 += __shfl_xor(sc1, off);
        }
        if (lane == 0) {
            size_t o = ((size_t)d * NS + s) * 2;
            T1b[o] = sa0; T1b[o + 1] = sa1;
            T2b[o] = sb0; T2b[o + 1] = sb1;
            Ta[o]  = sc0; Ta[o + 1]  = sc1;
        }
    }
}

// ------- main: 256-thr/4-wave blocks, reg-staged fp32->bf16, bf16 LDS dbuf, fused tanh+proj -------
__global__ __launch_bounds__(256, 4)
void k_main(const float* __restrict__ xbert, const float* __restrict__ xalb,
            const unsigned short* __restrict__ Wq,
            const float* __restrict__ bdb, const float* __restrict__ bda,
            const float* __restrict__ wpb, const float* __restrict__ wpa,
            float* __restrict__ pws, int Brows) {
    __shared__ __align__(16) short xsb[2][BM * 64];      // 2 x 8 KB bf16 chunks (row-XOR swizzled)
    __shared__ float outp[4][BM][2];                     // 2 KB

    const int tid = threadIdx.x;
    const int lane = tid & 63;
    const int wid = tid >> 6;                            // 0..3
    const int l15 = lane & 15;
    const int lhi = lane >> 4;                           // 0..3
    const int xorv = (l15 & 7) << 4;                     // A-frag read swizzle

    const int bid = blockIdx.x;
    const int nq = (bid >> 3) & 3;                       // n-quarter 0..3
    const int mtile = (bid & 7) | ((bid >> 5) << 3);
    const int G = nq * 4 + wid;                          // 48-col block index 0..15

    // staging: thread -> rows (tid>>4)+{0,16,32,48}, float cols (tid&15)*4..+4
    const int srow = tid >> 4;                           // 0..15
    const size_t rowoff0 = ((size_t)mtile * BM + srow) * D + (tid & 15) * 4;

    // cvt write offsets (swizzled bf16); (srow+16i)&7 == srow&7
    const int cvw0 = srow * 128 + (((tid & 15) * 8) ^ ((srow & 7) << 4));

    float outv = 0.0f;
    f32x4 acc[4][3];
    #pragma unroll
    for (int mi = 0; mi < 4; ++mi)
        #pragma unroll
        for (int ni = 0; ni < 3; ++ni)
            acc[mi][ni] = (f32x4){0.f, 0.f, 0.f, 0.f};

    float4 s0a, s0b, s0c, s0d, s1a, s1b, s1c, s1d;

    #define ISSUE(tgt, A, Bv, C, Dv) do {                                    \
        const float* xg_ = ((tgt) < NCHM) ? xbert : xalb;                    \
        const int lc_ = ((tgt) < NCHM) ? (tgt) : (tgt) - NCHM;               \
        const float* p_ = xg_ + rowoff0 + lc_ * 64;                          \
        A  = *(const float4*)(p_);                                           \
        Bv = *(const float4*)(p_ + 16 * D);                                  \
        C  = *(const float4*)(p_ + 32 * D);                                  \
        Dv = *(const float4*)(p_ + 48 * D);                                  \
    } while (0)

    #define CVTW(A, Bv, C, Dv, dbuf) do {                                    \
        char* b_ = (char*)&xsb[dbuf][0] + cvw0;                              \
        *(short4v*)(b_)        = cvt4(A);                                    \
        *(short4v*)(b_ + 2048) = cvt4(Bv);                                   \
        *(short4v*)(b_ + 4096) = cvt4(C);                                    \
        *(short4v*)(b_ + 6144) = cvt4(Dv);                                   \
    } while (0)

    #define MFMA_CHUNK(cb) do {                                              \
        const char* xbase_ = (const char*)&xsb[cb][0];                       \
        __builtin_amdgcn_s_setprio(1);                                       \
        _Pragma("unroll")                                                    \
        for (int klo = 0; klo < 2; ++klo) {                                  \
            short8v bv[3];                                                   \
            _Pragma("unroll")                                                \
            for (int ni = 0; ni < 3; ++ni)                                   \
                bv[ni] = *(const short8v*)(wqp + (klo * 3 + ni) * 512);      \
            _Pragma("unroll")                                                \
            for (int mi = 0; mi < 4; ++mi) {                                 \
                short8v av = *(const short8v*)(xbase_ + (mi * 16 + l15) * 128 \
                                 + ((klo * 64 + lhi * 16) ^ xorv));          \
                _Pragma("unroll")                                            \
                for (int ni = 0; ni < 3; ++ni)                               \
                    acc[mi][ni] = __builtin_amdgcn_mfma_f32_16x16x32_bf16(av, bv[ni], acc[mi][ni], 0, 0, 0); \
            }                                                                \
        }                                                                    \
        __builtin_amdgcn_s_setprio(0);                                       \
        wqp += 3072;                                                         \
    } while (0)

    #define EPILOGUE(mm) do {                                                \
        const float* bd_ = (mm) ? bda : bdb;                                 \
        const float* wp_ = (mm) ? wpa : wpb;                                 \
        float bdv[3], w0v[3], w1v[3];                                        \
        _Pragma("unroll")                                                    \
        for (int ni = 0; ni < 3; ++ni) {                                     \
            int n = G * 48 + ni * 16 + l15;                                  \
            bdv[ni] = bd_[n]; w0v[ni] = wp_[n]; w1v[ni] = wp_[D + n];        \
        }                                                                    \
        float ps[4][4][2] = {};                                              \
        _Pragma("unroll")                                                    \
        for (int mi = 0; mi < 4; ++mi)                                       \
            _Pragma("unroll")                                                \
            for (int ni = 0; ni < 3; ++ni)                                   \
                _Pragma("unroll")                                            \
                for (int r = 0; r < 4; ++r) {                                \
                    float t = fast_tanh(acc[mi][ni][r] + bdv[ni]);           \
                    ps[mi][r][0] += t * w0v[ni];                             \
                    ps[mi][r][1] += t * w1v[ni];                             \
                }                                                            \
        _Pragma("unroll")                                                    \
        for (int mi = 0; mi < 4; ++mi)                                       \
            _Pragma("unroll")                                                \
            for (int r = 0; r < 4; ++r)                                      \
                _Pragma("unroll")                                            \
                for (int cc = 0; cc < 2; ++cc) {                             \
                    float v = ps[mi][r][cc];                                 \
                    v += __shfl_xor(v, 1); v += __shfl_xor(v, 2);            \
                    v += __shfl_xor(v, 4); v += __shfl_xor(v, 8);            \
                    ps[mi][r][cc] = v;                                       \
                }                                                            \
        if (l15 == 0) {                                                      \
            _Pragma("unroll")                                                \
            for (int mi = 0; mi < 4; ++mi)                                   \
                _Pragma("unroll")                                            \
                for (int r = 0; r < 4; ++r) {                                \
                    int row = mi * 16 + lhi * 4 + r;                         \
                    outp[wid][row][0] = ps[mi][r][0];                        \
                    outp[wid][row][1] = ps[mi][r][1];                        \
                }                                                            \
        }                                                                    \
        __syncthreads();                                                     \
        if (tid < 128) {                                                     \
            int row = tid >> 1, cc = tid & 1;                                \
            float s = 0.0f;                                                  \
            _Pragma("unroll")                                                \
            for (int w = 0; w < 4; ++w) s += outp[w][row][cc];               \
            outv += s;                                                       \
        }                                                                    \
        _Pragma("unroll")                                                    \
        for (int mi = 0; mi < 4; ++mi)                                       \
            _Pragma("unroll")                                                \
            for (int ni = 0; ni < 3; ++ni)                                   \
                acc[mi][ni] = (f32x4){0.f, 0.f, 0.f, 0.f};                   \
    } while (0)

    // ---- prologue: chunks 0 and 1 into regs; chunk 0 -> xsb[0] ----
    ISSUE(0, s0a, s0b, s0c, s0d);
    ISSUE(1, s1a, s1b, s1c, s1d);
    CVTW(s0a, s0b, s0c, s0d, 0);
    __syncthreads();

    #pragma unroll 1
    for (int m = 0; m < 2; ++m) {
        const unsigned short* wqp = Wq + ((size_t)(m * 16 + G) * NGK * 3) * 512 + lane * 8;
        #pragma unroll 1
        for (int lc = 0; lc < NCHM; lc += 2) {
            const int g = m * NCHM + lc;
            // ---- even chunk (buf 0) ----
            MFMA_CHUNK(0);
            if (g + 2 < 2 * NCHM) ISSUE(g + 2, s0a, s0b, s0c, s0d);
            CVTW(s1a, s1b, s1c, s1d, 1);                 // chunk g+1 -> xsb[1]
            __syncthreads();
            // ---- odd chunk (buf 1) ----
            MFMA_CHUNK(1);
            if (g + 3 < 2 * NCHM) ISSUE(g + 3, s1a, s1b, s1c, s1d);
            if (g + 2 < 2 * NCHM) CVTW(s0a, s0b, s0c, s0d, 0);   // chunk g+2 -> xsb[0]
            if (lc == NCHM - 2) { EPILOGUE(m); } else { __syncthreads(); }
        }
    }
    #undef ISSUE
    #undef CVTW
    #undef MFMA_CHUNK
    #undef EPILOGUE

    // ---- write this block's partial (per n-quarter) ----
    if (tid < 128) {
        int row = tid >> 1, cc = tid & 1;
        size_t R = (size_t)mtile * BM + row;
        pws[((size_t)nq * Brows + R) * 2 + cc] = outv;
    }
}

// ---------------- combine: n-quarter partials + gather + biases ----------------
__global__ void k_combine(const float* __restrict__ pws, const int* __restrict__ pairs,
                          const float* __restrict__ T1b, const float* __restrict__ T2b,
                          const float* __restrict__ Ta,
                          const float* __restrict__ bpb, const float* __restrict__ bpa,
                          const float* __restrict__ b1b, const float* __restrict__ b2b,
                          const float* __restrict__ b1a, const float* __restrict__ b2a,
                          float* __restrict__ out, int B) {
    int r = blockIdx.x * blockDim.x + threadIdx.x;
    if (r >= B) return;
    const int* pr = pairs + (size_t)r * 3;
    int i0 = pr[0], j = pr[1], k2 = pr[2];
    #pragma unroll
    for (int c = 0; c < 2; ++c) {
        float g = T1b[((size_t)i0 * NS + j) * 2 + c]
                + T2b[((size_t)i0 * NS + k2) * 2 + c]
                + Ta[((size_t)i0 * NS + j) * 2 + c];
        float bias = bpb[c] + bpa[c] + b1b[c] + b2b[c] + b1a[c] + b2a[c];
        float s = pws[(size_t)r * 2 + c] + pws[((size_t)B + r) * 2 + c]
                + pws[((size_t)2 * B + r) * 2 + c] + pws[((size_t)3 * B + r) * 2 + c];
        out[(size_t)r * 2 + c] = s + g + bias;
    }
}

extern "C" void kernel_launch(void* const* d_in, const int* in_sizes, int n_in,
                              void* d_out, int out_size, void* d_ws, size_t ws_size,
                              hipStream_t stream) {
    const float* xb   = (const float*)d_in[0];
    const float* db   = (const float*)d_in[1];
    const int*   pairs= (const int*)d_in[2];
    const float* xa   = (const float*)d_in[3];
    const float* da   = (const float*)d_in[4];
    const float* Wdb  = (const float*)d_in[5];
    const float* bdb  = (const float*)d_in[6];
    const float* Wda  = (const float*)d_in[7];
    const float* bda  = (const float*)d_in[8];
    const float* Wpb  = (const float*)d_in[9];
    const float* bpb  = (const float*)d_in[10];
    const float* Wpa  = (const float*)d_in[11];
    const float* bpa  = (const float*)d_in[12];
    const float* W1b  = (const float*)d_in[13];
    const float* b1b  = (const float*)d_in[14];
    const float* W2b  = (const float*)d_in[15];
    const float* b2b  = (const float*)d_in[16];
    const float* W1a  = (const float*)d_in[17];
    const float* b1a  = (const float*)d_in[18];
    const float* W2a  = (const float*)d_in[19];
    const float* b2a  = (const float*)d_in[20];
    float* out = (float*)d_out;

    const int B = in_sizes[0] / D;                       // 65536

    char* ws = (char*)d_ws;
    int* flags = (int*)ws;                               // 2048 B
    unsigned short* Wq = (unsigned short*)(ws + 2048);   // 2,359,296 B
    float* T1b = (float*)(ws + 2048 + 2359296);
    float* T2b = T1b + NTAB * NS * 2;
    float* Ta  = T2b + NTAB * NS * 2;
    float* pws = Ta + NTAB * NS * 2;                     // 4*B*2 floats = 2 MB

    hipMemsetAsync(flags, 0, NTAB * sizeof(int), stream);
    k_scan_pairs<<<(B + 255) / 256, 256, 0, stream>>>(pairs, flags, B);
    const int conv_blocks = (2 * NGN * NGK + 3) / 4;     // 576
    k_tables_convq<<<NTAB * 4 + conv_blocks, 256, 0, stream>>>(
        db, da, W1b, W2b, W1a, W2a, flags, T1b, T2b, Ta, Wdb, Wda, Wq);
    k_main<<<(B / BM) * 4, 256, 0, stream>>>(xb, xa, Wq, bdb, bda, Wpb, Wpa, pws, B);
    k_combine<<<(B + 255) / 256, 256, 0, stream>>>(pws, pairs, T1b, T2b, Ta,
                                                   bpb, bpa, b1b, b2b, b1a, b2a, out, B);
}

// Round 7
// 382.057 us; speedup vs baseline: 2.5827x; 2.1051x over previous
//
#include <hip/hip_runtime.h>
#include <hip/hip_bf16.h>

#define D 768
#define BM 64
#define NCHM 12          // K-chunks per model (768/64)
#define NTAB 512         // ND
#define NS 64
#define NGK 24           // kc granules per row (768/32)
#define NGN 48           // n-groups (768/16)

typedef short short8v __attribute__((ext_vector_type(8)));
typedef short short4v __attribute__((ext_vector_type(4)));
typedef float f32x4 __attribute__((ext_vector_type(4)));

typedef const __attribute__((address_space(1))) void* gptr_t;
typedef __attribute__((address_space(3))) void* lptr_t;

static __device__ __forceinline__ void gload16(const void* g, void* l) {
    __builtin_amdgcn_global_load_lds((gptr_t)g, (lptr_t)l, 16, 0, 0);
}

static __device__ __forceinline__ short8v cvt8(float4 a, float4 b) {
    union { short8v v; __hip_bfloat162 h[4]; } u;
    u.h[0] = __float22bfloat162_rn({a.x, a.y});
    u.h[1] = __float22bfloat162_rn({a.z, a.w});
    u.h[2] = __float22bfloat162_rn({b.x, b.y});
    u.h[3] = __float22bfloat162_rn({b.z, b.w});
    return u.v;
}

static __device__ __forceinline__ short4v cvt4(float4 a) {
    union { short4v v; __hip_bfloat162 h[2]; } u;
    u.h[0] = __float22bfloat162_rn({a.x, a.y});
    u.h[1] = __float22bfloat162_rn({a.z, a.w});
    return u.v;
}

static __device__ __forceinline__ float fast_tanh(float x) {
    float e = __expf(2.0f * x);
    return 1.0f - 2.0f * __builtin_amdgcn_rcpf(e + 1.0f);
}

static __device__ __forceinline__ float dot4(float4 a, float4 b) {
    return a.x * b.x + a.y * b.y + a.z * b.z + a.w * b.w;
}

// ---------------- pairs scan: mark live table rows ----------------
__global__ void k_scan_pairs(const int* __restrict__ pairs, int* __restrict__ flags, int B) {
    int i = blockIdx.x * blockDim.x + threadIdx.x;
    if (i < B) {
        int idx = pairs[(size_t)i * 3];
        if (idx >= 0 && idx < NTAB) atomicOr(&flags[idx], 1);
    }
}

// ---- fused: gather tables (bid < NTAB*4) + W fp32->bf16 fragment pack (rest) ----
__global__ void k_tables_convq(const float* __restrict__ db, const float* __restrict__ da,
                               const float* __restrict__ W1b, const float* __restrict__ W2b,
                               const float* __restrict__ W1a, const float* __restrict__ W2a,
                               const int* __restrict__ flags,
                               float* __restrict__ T1b, float* __restrict__ T2b, float* __restrict__ Ta,
                               const float* __restrict__ wb_f, const float* __restrict__ wa_f,
                               unsigned short* __restrict__ Wq) {
    int bid = blockIdx.x;
    if (bid >= NTAB * 4) {
        int widx = (bid - NTAB * 4) * 4 + (threadIdx.x >> 6);
        if (widx >= 2 * NGN * NGK) return;
        int model = widx / (NGN * NGK);
        int rem = widx % (NGN * NGK);
        int g = rem / NGK;
        int kc = rem % NGK;
        int l = threadIdx.x & 63;
        const float* Wsrc = model ? wa_f : wb_f;
        const float* src = Wsrc + (size_t)(g * 16 + (l & 15)) * D + kc * 32 + (l >> 4) * 8;
        float4 f0 = *(const float4*)src;
        float4 f1 = *(const float4*)(src + 4);
        *(short8v*)(Wq + ((((size_t)model * NGN + g) * NGK + kc) * 64 + l) * 8) = cvt8(f0, f1);
        return;
    }
    int d = bid >> 2;
    int q = bid & 3;
    if (!flags[d]) return;
    int lane = threadIdx.x & 63;
    int wid = threadIdx.x >> 6;                         // 0..3

    float4 a0[3], a1[3], b0[3], b1[3], c0[3], c1[3];
    #pragma unroll
    for (int i = 0; i < 3; ++i) {
        a0[i] = ((const float4*)W1b)[lane + 64 * i];
        a1[i] = ((const float4*)(W1b + D))[lane + 64 * i];
        b0[i] = ((const float4*)W2b)[lane + 64 * i];
        b1[i] = ((const float4*)(W2b + D))[lane + 64 * i];
        float4 p = ((const float4*)W1a)[lane + 64 * i];
        float4 qv = ((const float4*)W2a)[lane + 64 * i];
        c0[i] = make_float4(p.x + qv.x, p.y + qv.y, p.z + qv.z, p.w + qv.w);
        p = ((const float4*)(W1a + D))[lane + 64 * i];
        qv = ((const float4*)(W2a + D))[lane + 64 * i];
        c1[i] = make_float4(p.x + qv.x, p.y + qv.y, p.z + qv.z, p.w + qv.w);
    }

    #pragma unroll
    for (int si = 0; si < 4; ++si) {
        int s = q * 16 + wid + si * 4;
        size_t roff = ((size_t)d * NS + s) * D;
        const float4* rb = (const float4*)(db + roff);
        const float4* ra = (const float4*)(da + roff);
        float sa0 = 0, sa1 = 0, sb0 = 0, sb1 = 0, sc0 = 0, sc1 = 0;
        #pragma unroll
        for (int i = 0; i < 3; ++i) {
            float4 xb = rb[lane + 64 * i];
            float4 xa = ra[lane + 64 * i];
            sa0 += dot4(xb, a0[i]); sa1 += dot4(xb, a1[i]);
            sb0 += dot4(xb, b0[i]); sb1 += dot4(xb, b1[i]);
            sc0 += dot4(xa, c0[i]); sc1 += dot4(xa, c1[i]);
        }
        #pragma unroll
        for (int off = 32; off; off >>= 1) {
            sa0 += __shfl_xor(sa0, off); sa1 += __shfl_xor(sa1, off);
            sb0 += __shfl_xor(sb0, off); sb1 += __shfl_xor(sb1, off);
            sc0 += __shfl_xor(sc0, off); sc1 += __shfl_xor(sc1, off);
        }
        if (lane == 0) {
            size_t o = ((size_t)d * NS + s) * 2;
            T1b[o] = sa0; T1b[o + 1] = sa1;
            T2b[o] = sb0; T2b[o + 1] = sb1;
            Ta[o]  = sc0; Ta[o + 1]  = sc1;
        }
    }
}

// ---- main: 3-deep glds fp32 ring -> coop bf16 cvt -> MFMA; counted vmcnt, raw barriers ----
__global__ __launch_bounds__(512, 8)
void k_main(const float* __restrict__ xbert, const float* __restrict__ xalb,
            const unsigned short* __restrict__ Wq,
            const float* __restrict__ bdb, const float* __restrict__ bda,
            const float* __restrict__ wpb, const float* __restrict__ wpa,
            float* __restrict__ pws, int Brows) {
    __shared__ __align__(16) float xs32[3][BM * 64];     // 3 x 16 KB fp32 ring
    __shared__ __align__(16) short xsb[2][BM * 64];      // 2 x  8 KB bf16 (row-XOR swizzled)
    __shared__ float outp[8][BM][2];                     // 4 KB   (total 69,632 B)

    const int tid = threadIdx.x;
    const int lane = tid & 63;
    const int wid = tid >> 6;                            // 0..7
    const int l15 = lane & 15;
    const int lhi = lane >> 4;                           // 0..3
    const int xorv = (l15 & 7) << 4;                     // A-frag read swizzle

    const int bid = blockIdx.x;
    const int nh = (bid >> 3) & 1;
    const int mtile = (bid & 7) | ((bid >> 4) << 3);
    const int nb16 = nh * 24 + wid * 3;                  // wave's first n-group

    // staging: thread -> rows (tid>>4) and +32, float cols (tid&15)*4..+4
    const int srow = tid >> 4;                           // 0..31
    const size_t rowoff1 = ((size_t)mtile * BM + srow) * D + (tid & 15) * 4;
    const size_t rowoff2 = rowoff1 + (size_t)32 * D;

    // cvt write offsets (swizzled bf16); (srow+32)&7 == srow&7
    const int cc2 = (tid & 15) * 8;
    const int cvw0 = srow * 128 + (cc2 ^ ((srow & 7) << 4));
    const int cvw1 = (srow + 32) * 128 + (cc2 ^ ((srow & 7) << 4));

    float outv = 0.0f;
    f32x4 acc[4][3];
    #pragma unroll
    for (int mi = 0; mi < 4; ++mi)
        #pragma unroll
        for (int ni = 0; ni < 3; ++ni)
            acc[mi][ni] = (f32x4){0.f, 0.f, 0.f, 0.f};

    // each wave's glds destination region is read back only by the same wave's CVT
    #define STAGE(cc, fbuf)                                                      \
        do {                                                                     \
            const int m_ = ((cc) >= NCHM) ? 1 : 0;                               \
            const float* xg_ = m_ ? xalb : xbert;                                \
            const int lc_ = (cc) - m_ * NCHM;                                    \
            gload16(xg_ + rowoff1 + lc_ * 64, &xs32[fbuf][wid * 256]);           \
            gload16(xg_ + rowoff2 + lc_ * 64, &xs32[fbuf][2048 + wid * 256]);    \
        } while (0)

    #define CVTL(sbuf, dbuf)                                                     \
        do {                                                                     \
            float4 fa_ = *(const float4*)&xs32[sbuf][tid * 4];                   \
            float4 fb_ = *(const float4*)&xs32[sbuf][2048 + tid * 4];            \
            *(short4v*)((char*)&xsb[dbuf][0] + cvw0) = cvt4(fa_);                \
            *(short4v*)((char*)&xsb[dbuf][0] + cvw1) = cvt4(fb_);                \
        } while (0)

    // raw barrier: drain LDS ops only — glds (vmem) stay in flight across it
    #define BAR()                                                                \
        do {                                                                     \
            asm volatile("s_waitcnt lgkmcnt(0)" ::: "memory");                   \
            __builtin_amdgcn_sched_barrier(0);                                   \
            __builtin_amdgcn_s_barrier();                                        \
        } while (0)

    // ---- prologue: 3 chunks in flight; chunk 0 -> xsb[0] ----
    STAGE(0, 0);
    STAGE(1, 1);
    STAGE(2, 2);
    asm volatile("s_waitcnt vmcnt(4)" ::: "memory");     // chunk 0 landed
    __builtin_amdgcn_sched_barrier(0);
    CVTL(0, 0);
    BAR();

    #pragma unroll 1
    for (int c = 0; c < 2 * NCHM; ++c) {
        const int m = (c >= NCHM) ? 1 : 0;
        const int lc = c - m * NCHM;
        const int cb = c & 1;

        // ---- MFMA chunk c from bf16 buffer ----
        {
            const char* xbase = (const char*)&xsb[cb][0];
            const unsigned short* wbase = Wq + ((size_t)m * NGN + nb16) * (NGK * 512);
            __builtin_amdgcn_s_setprio(1);
            #pragma unroll
            for (int klo = 0; klo < 2; ++klo) {
                const int kc = lc * 2 + klo;
                short8v bv[3];
                #pragma unroll
                for (int ni = 0; ni < 3; ++ni)
                    bv[ni] = *(const short8v*)(wbase + ((size_t)ni * NGK + kc) * 512 + lane * 8);
                #pragma unroll
                for (int mi = 0; mi < 4; ++mi) {
                    short8v av = *(const short8v*)(xbase + (mi * 16 + l15) * 128 +
                                                   ((klo * 64 + lhi * 16) ^ xorv));
                    #pragma unroll
                    for (int ni = 0; ni < 3; ++ni)
                        acc[mi][ni] = __builtin_amdgcn_mfma_f32_16x16x32_bf16(av, bv[ni], acc[mi][ni], 0, 0, 0);
                }
            }
            __builtin_amdgcn_s_setprio(0);
        }

        // ---- stage chunk c+3 AFTER the bv loads (keeps its glds FIFO-young) ----
        if (c + 3 < 2 * NCHM) STAGE(c + 3, c % 3);

        // ---- convert chunk c+1 (own-wave data): counted wait, never a full drain mid-loop ----
        if (c + 1 < 2 * NCHM) {
            if (c < 21)       { asm volatile("s_waitcnt vmcnt(4)" ::: "memory"); }
            else if (c == 21) { asm volatile("s_waitcnt vmcnt(2)" ::: "memory"); }
            else              { asm volatile("s_waitcnt vmcnt(0)" ::: "memory"); }
            __builtin_amdgcn_sched_barrier(0);
            CVTL((c + 1) % 3, cb ^ 1);
        }

        if (lc == NCHM - 1) {
            // ---- epilogue for model m: tanh + 2-col projection ----
            const float* bd = m ? bda : bdb;
            const float* wp = m ? wpa : wpb;
            float bdv[3], w0v[3], w1v[3];
            #pragma unroll
            for (int ni = 0; ni < 3; ++ni) {
                int n = nh * 384 + wid * 48 + ni * 16 + l15;
                bdv[ni] = bd[n];
                w0v[ni] = wp[n];
                w1v[ni] = wp[D + n];
            }
            float ps[4][4][2] = {};
            #pragma unroll
            for (int mi = 0; mi < 4; ++mi)
                #pragma unroll
                for (int ni = 0; ni < 3; ++ni)
                    #pragma unroll
                    for (int r = 0; r < 4; ++r) {
                        float t = fast_tanh(acc[mi][ni][r] + bdv[ni]);
                        ps[mi][r][0] += t * w0v[ni];
                        ps[mi][r][1] += t * w1v[ni];
                    }
            #pragma unroll
            for (int mi = 0; mi < 4; ++mi)
                #pragma unroll
                for (int r = 0; r < 4; ++r)
                    #pragma unroll
                    for (int cc = 0; cc < 2; ++cc) {
                        float v = ps[mi][r][cc];
                        v += __shfl_xor(v, 1);
                        v += __shfl_xor(v, 2);
                        v += __shfl_xor(v, 4);
                        v += __shfl_xor(v, 8);
                        ps[mi][r][cc] = v;
                    }
            if (l15 == 0) {
                #pragma unroll
                for (int mi = 0; mi < 4; ++mi)
                    #pragma unroll
                    for (int r = 0; r < 4; ++r) {
                        int row = mi * 16 + lhi * 4 + r;
                        outp[wid][row][0] = ps[mi][r][0];
                        outp[wid][row][1] = ps[mi][r][1];
                    }
            }
            BAR();                                       // orders outp and serves as chunk barrier
            if (tid < 128) {
                int row = tid >> 1, cc = tid & 1;
                float s = 0.0f;
                #pragma unroll
                for (int w = 0; w < 8; ++w) s += outp[w][row][cc];
                outv += s;
            }
            #pragma unroll
            for (int mi = 0; mi < 4; ++mi)
                #pragma unroll
                for (int ni = 0; ni < 3; ++ni)
                    acc[mi][ni] = (f32x4){0.f, 0.f, 0.f, 0.f};
        } else {
            BAR();
        }
    }
    #undef STAGE
    #undef CVTL
    #undef BAR

    // ---- write this block's partial (per n-half) ----
    if (tid < 128) {
        int row = tid >> 1, cc = tid & 1;
        size_t R = (size_t)mtile * BM + row;
        pws[((size_t)nh * Brows + R) * 2 + cc] = outv;
    }
}

// ---------------- combine: n-half partials + gather + biases ----------------
__global__ void k_combine(const float* __restrict__ pws, const int* __restrict__ pairs,
                          const float* __restrict__ T1b, const float* __restrict__ T2b,
                          const float* __restrict__ Ta,
                          const float* __restrict__ bpb, const float* __restrict__ bpa,
                          const float* __restrict__ b1b, const float* __restrict__ b2b,
                          const float* __restrict__ b1a, const float* __restrict__ b2a,
                          float* __restrict__ out, int B) {
    int r = blockIdx.x * blockDim.x + threadIdx.x;
    if (r >= B) return;
    const int* pr = pairs + (size_t)r * 3;
    int i0 = pr[0], j = pr[1], k2 = pr[2];
    #pragma unroll
    for (int c = 0; c < 2; ++c) {
        float g = T1b[((size_t)i0 * NS + j) * 2 + c]
                + T2b[((size_t)i0 * NS + k2) * 2 + c]
                + Ta[((size_t)i0 * NS + j) * 2 + c];
        float bias = bpb[c] + bpa[c] + b1b[c] + b2b[c] + b1a[c] + b2a[c];
        out[(size_t)r * 2 + c] = pws[(size_t)r * 2 + c] + pws[((size_t)B + r) * 2 + c] + g + bias;
    }
}

extern "C" void kernel_launch(void* const* d_in, const int* in_sizes, int n_in,
                              void* d_out, int out_size, void* d_ws, size_t ws_size,
                              hipStream_t stream) {
    const float* xb   = (const float*)d_in[0];
    const float* db   = (const float*)d_in[1];
    const int*   pairs= (const int*)d_in[2];
    const float* xa   = (const float*)d_in[3];
    const float* da   = (const float*)d_in[4];
    const float* Wdb  = (const float*)d_in[5];
    const float* bdb  = (const float*)d_in[6];
    const float* Wda  = (const float*)d_in[7];
    const float* bda  = (const float*)d_in[8];
    const float* Wpb  = (const float*)d_in[9];
    const float* bpb  = (const float*)d_in[10];
    const float* Wpa  = (const float*)d_in[11];
    const float* bpa  = (const float*)d_in[12];
    const float* W1b  = (const float*)d_in[13];
    const float* b1b  = (const float*)d_in[14];
    const float* W2b  = (const float*)d_in[15];
    const float* b2b  = (const float*)d_in[16];
    const float* W1a  = (const float*)d_in[17];
    const float* b1a  = (const float*)d_in[18];
    const float* W2a  = (const float*)d_in[19];
    const float* b2a  = (const float*)d_in[20];
    float* out = (float*)d_out;

    const int B = in_sizes[0] / D;                       // 65536

    char* ws = (char*)d_ws;
    int* flags = (int*)ws;                               // 2048 B
    unsigned short* Wq = (unsigned short*)(ws + 2048);   // 2,359,296 B
    float* T1b = (float*)(ws + 2048 + 2359296);
    float* T2b = T1b + NTAB * NS * 2;
    float* Ta  = T2b + NTAB * NS * 2;
    float* pws = Ta + NTAB * NS * 2;                     // 2*B*2 floats

    hipMemsetAsync(flags, 0, NTAB * sizeof(int), stream);
    k_scan_pairs<<<(B + 255) / 256, 256, 0, stream>>>(pairs, flags, B);
    const int conv_blocks = (2 * NGN * NGK + 3) / 4;     // 576
    k_tables_convq<<<NTAB * 4 + conv_blocks, 256, 0, stream>>>(
        db, da, W1b, W2b, W1a, W2a, flags, T1b, T2b, Ta, Wdb, Wda, Wq);
    k_main<<<(B / BM) * 2, 512, 0, stream>>>(xb, xa, Wq, bdb, bda, Wpb, Wpa, pws, B);
    k_combine<<<(B + 255) / 256, 256, 0, stream>>>(pws, pairs, T1b, T2b, Ta,
                                                   bpb, bpa, b1b, b2b, b1a, b2a, out, B);
}

// Round 8
// 347.496 us; speedup vs baseline: 2.8396x; 1.0995x over previous
//
#include <hip/hip_runtime.h>
#include <hip/hip_bf16.h>

#define D 768
#define BM 64
#define NCHM 12          // K-chunks per model (768/64)
#define NTAB 512         // ND
#define NS 64
#define NGK 24           // kc granules per row (768/32)
#define NGN 48           // n-groups (768/16)

typedef short short8v __attribute__((ext_vector_type(8)));
typedef short short4v __attribute__((ext_vector_type(4)));
typedef float f32x4 __attribute__((ext_vector_type(4)));

typedef const __attribute__((address_space(1))) void* gptr_t;
typedef __attribute__((address_space(3))) void* lptr_t;

static __device__ __forceinline__ void gload16(const void* g, void* l) {
    __builtin_amdgcn_global_load_lds((gptr_t)g, (lptr_t)l, 16, 0, 0);
}

static __device__ __forceinline__ short8v cvt8(float4 a, float4 b) {
    union { short8v v; __hip_bfloat162 h[4]; } u;
    u.h[0] = __float22bfloat162_rn({a.x, a.y});
    u.h[1] = __float22bfloat162_rn({a.z, a.w});
    u.h[2] = __float22bfloat162_rn({b.x, b.y});
    u.h[3] = __float22bfloat162_rn({b.z, b.w});
    return u.v;
}

static __device__ __forceinline__ short4v cvt4(float4 a) {
    union { short4v v; __hip_bfloat162 h[2]; } u;
    u.h[0] = __float22bfloat162_rn({a.x, a.y});
    u.h[1] = __float22bfloat162_rn({a.z, a.w});
    return u.v;
}

static __device__ __forceinline__ float fast_tanh(float x) {
    float e = __expf(2.0f * x);
    return 1.0f - 2.0f * __builtin_amdgcn_rcpf(e + 1.0f);
}

static __device__ __forceinline__ float dot4(float4 a, float4 b) {
    return a.x * b.x + a.y * b.y + a.z * b.z + a.w * b.w;
}

// ---------------- pairs scan: mark live table rows ----------------
__global__ void k_scan_pairs(const int* __restrict__ pairs, int* __restrict__ flags, int B) {
    int i = blockIdx.x * blockDim.x + threadIdx.x;
    if (i < B) {
        int idx = pairs[(size_t)i * 3];
        if (idx >= 0 && idx < NTAB) atomicOr(&flags[idx], 1);
    }
}

// ---- fused: gather tables (bid < NTAB*4) + W fp32->bf16 fragment pack (rest) ----
__global__ void k_tables_convq(const float* __restrict__ db, const float* __restrict__ da,
                               const float* __restrict__ W1b, const float* __restrict__ W2b,
                               const float* __restrict__ W1a, const float* __restrict__ W2a,
                               const int* __restrict__ flags,
                               float* __restrict__ T1b, float* __restrict__ T2b, float* __restrict__ Ta,
                               const float* __restrict__ wb_f, const float* __restrict__ wa_f,
                               unsigned short* __restrict__ Wq) {
    int bid = blockIdx.x;
    if (bid >= NTAB * 4) {
        int widx = (bid - NTAB * 4) * 4 + (threadIdx.x >> 6);
        if (widx >= 2 * NGN * NGK) return;
        int model = widx / (NGN * NGK);
        int rem = widx % (NGN * NGK);
        int g = rem / NGK;
        int kc = rem % NGK;
        int l = threadIdx.x & 63;
        const float* Wsrc = model ? wa_f : wb_f;
        const float* src = Wsrc + (size_t)(g * 16 + (l & 15)) * D + kc * 32 + (l >> 4) * 8;
        float4 f0 = *(const float4*)src;
        float4 f1 = *(const float4*)(src + 4);
        *(short8v*)(Wq + ((((size_t)model * NGN + g) * NGK + kc) * 64 + l) * 8) = cvt8(f0, f1);
        return;
    }
    int d = bid >> 2;
    int q = bid & 3;
    if (!flags[d]) return;
    int lane = threadIdx.x & 63;
    int wid = threadIdx.x >> 6;                         // 0..3

    float4 a0[3], a1[3], b0[3], b1[3], c0[3], c1[3];
    #pragma unroll
    for (int i = 0; i < 3; ++i) {
        a0[i] = ((const float4*)W1b)[lane + 64 * i];
        a1[i] = ((const float4*)(W1b + D))[lane + 64 * i];
        b0[i] = ((const float4*)W2b)[lane + 64 * i];
        b1[i] = ((const float4*)(W2b + D))[lane + 64 * i];
        float4 p = ((const float4*)W1a)[lane + 64 * i];
        float4 qv = ((const float4*)W2a)[lane + 64 * i];
        c0[i] = make_float4(p.x + qv.x, p.y + qv.y, p.z + qv.z, p.w + qv.w);
        p = ((const float4*)(W1a + D))[lane + 64 * i];
        qv = ((const float4*)(W2a + D))[lane + 64 * i];
        c1[i] = make_float4(p.x + qv.x, p.y + qv.y, p.z + qv.z, p.w + qv.w);
    }

    #pragma unroll
    for (int si = 0; si < 4; ++si) {
        int s = q * 16 + wid + si * 4;
        size_t roff = ((size_t)d * NS + s) * D;
        const float4* rb = (const float4*)(db + roff);
        const float4* ra = (const float4*)(da + roff);
        float sa0 = 0, sa1 = 0, sb0 = 0, sb1 = 0, sc0 = 0, sc1 = 0;
        #pragma unroll
        for (int i = 0; i < 3; ++i) {
            float4 xb = rb[lane + 64 * i];
            float4 xa = ra[lane + 64 * i];
            sa0 += dot4(xb, a0[i]); sa1 += dot4(xb, a1[i]);
            sb0 += dot4(xb, b0[i]); sb1 += dot4(xb, b1[i]);
            sc0 += dot4(xa, c0[i]); sc1 += dot4(xa, c1[i]);
        }
        #pragma unroll
        for (int off = 32; off; off >>= 1) {
            sa0 += __shfl_xor(sa0, off); sa1 += __shfl_xor(sa1, off);
            sb0 += __shfl_xor(sb0, off); sb1 += __shfl_xor(sb1, off);
            sc0 += __shfl_xor(sc0, off); sc1 += __shfl_xor(sc1, off);
        }
        if (lane == 0) {
            size_t o = ((size_t)d * NS + s) * 2;
            T1b[o] = sa0; T1b[o + 1] = sa1;
            T2b[o] = sb0; T2b[o + 1] = sb1;
            Ta[o]  = sc0; Ta[o + 1]  = sc1;
        }
    }
}

// ---- main: glds fp32 ring -> coop cvt (top) -> MFMA with reg-prefetched B; counted vmcnt ----
__global__ __launch_bounds__(512, 4)
void k_main(const float* __restrict__ xbert, const float* __restrict__ xalb,
            const unsigned short* __restrict__ Wq,
            const float* __restrict__ bdb, const float* __restrict__ bda,
            const float* __restrict__ wpb, const float* __restrict__ wpa,
            float* __restrict__ pws, int Brows) {
    __shared__ __align__(16) float xs32[3][BM * 64];     // 3 x 16 KB fp32 ring
    __shared__ __align__(16) short xsb[2][BM * 64];      // 2 x  8 KB bf16 (row-XOR swizzled)
    __shared__ float outp[8][BM][2];                     // 4 KB   (total 69,632 B)

    const int tid = threadIdx.x;
    const int lane = tid & 63;
    const int wid = tid >> 6;                            // 0..7
    const int l15 = lane & 15;
    const int lhi = lane >> 4;                           // 0..3
    const int xorv = (l15 & 7) << 4;                     // A-frag read swizzle

    const int bid = blockIdx.x;
    const int nh = (bid >> 3) & 1;
    const int mtile = (bid & 7) | ((bid >> 4) << 3);
    const int nb16 = nh * 24 + wid * 3;                  // wave's first n-group

    // staging: thread -> rows (tid>>4) and +32, float cols (tid&15)*4..+4
    const int srow = tid >> 4;                           // 0..31
    const size_t rowoff1 = ((size_t)mtile * BM + srow) * D + (tid & 15) * 4;
    const size_t rowoff2 = rowoff1 + (size_t)32 * D;

    // cvt write offsets (swizzled bf16); (srow+32)&7 == srow&7
    const int cc2 = (tid & 15) * 8;
    const int cvw0 = srow * 128 + (cc2 ^ ((srow & 7) << 4));
    const int cvw1 = (srow + 32) * 128 + (cc2 ^ ((srow & 7) << 4));

    float outv = 0.0f;
    f32x4 acc[4][3];
    #pragma unroll
    for (int mi = 0; mi < 4; ++mi)
        #pragma unroll
        for (int ni = 0; ni < 3; ++ni)
            acc[mi][ni] = (f32x4){0.f, 0.f, 0.f, 0.f};

    short8v bvp[3];                                      // klo=0 B-frags, prefetched 1 chunk ahead

    #define STAGE(cc, fbuf)                                                      \
        do {                                                                     \
            const int m_ = ((cc) >= NCHM) ? 1 : 0;                               \
            const float* xg_ = m_ ? xalb : xbert;                                \
            const int lc_ = (cc) - m_ * NCHM;                                    \
            gload16(xg_ + rowoff1 + lc_ * 64, &xs32[fbuf][wid * 256]);           \
            gload16(xg_ + rowoff2 + lc_ * 64, &xs32[fbuf][2048 + wid * 256]);    \
        } while (0)

    #define CVTL(sbuf, dbuf)                                                     \
        do {                                                                     \
            float4 fa_ = *(const float4*)&xs32[sbuf][tid * 4];                   \
            float4 fb_ = *(const float4*)&xs32[sbuf][2048 + tid * 4];            \
            *(short4v*)((char*)&xsb[dbuf][0] + cvw0) = cvt4(fa_);                \
            *(short4v*)((char*)&xsb[dbuf][0] + cvw1) = cvt4(fb_);                \
        } while (0)

    // klo=0 B-fragment prefetch for chunk cc
    #define BVP(cc)                                                              \
        do {                                                                     \
            const int m_ = ((cc) >= NCHM) ? 1 : 0;                               \
            const int lc_ = (cc) - m_ * NCHM;                                    \
            const unsigned short* wb_ = Wq +                                     \
                ((size_t)(m_ * NGN + nb16) * NGK + lc_ * 2) * 512 + lane * 8;    \
            bvp[0] = *(const short8v*)(wb_);                                     \
            bvp[1] = *(const short8v*)(wb_ + (size_t)NGK * 512);                 \
            bvp[2] = *(const short8v*)(wb_ + (size_t)2 * NGK * 512);             \
        } while (0)

    // raw barrier: drain LDS ops only — vmem stays in flight across it
    #define BAR()                                                                \
        do {                                                                     \
            asm volatile("s_waitcnt lgkmcnt(0)" ::: "memory");                   \
            __builtin_amdgcn_sched_barrier(0);                                   \
            __builtin_amdgcn_s_barrier();                                        \
        } while (0)

    // ---- prologue: bvp(0) + 3 staged chunks; chunk 0 -> xsb[0] ----
    BVP(0);
    STAGE(0, 0);
    STAGE(1, 1);
    STAGE(2, 2);
    asm volatile("s_waitcnt vmcnt(4)" ::: "memory");     // chunk 0 landed (STAGE(1,2) younger)
    __builtin_amdgcn_sched_barrier(0);
    CVTL(0, 0);
    BAR();

    #pragma unroll 1
    for (int c = 0; c < 2 * NCHM; ++c) {
        const int m = (c >= NCHM) ? 1 : 0;
        const int lc = c - m * NCHM;
        const int cb = c & 1;

        // ---- convert chunk c+1 FIRST (independent of MFMA(c); hides under it) ----
        if (c + 1 < 2 * NCHM) {
            if (c == 0)       { asm volatile("s_waitcnt vmcnt(2)" ::: "memory"); }
            else if (c <= 21) { asm volatile("s_waitcnt vmcnt(8)" ::: "memory"); }
            else              { asm volatile("s_waitcnt vmcnt(6)" ::: "memory"); }
            __builtin_amdgcn_sched_barrier(0);
            CVTL((c + 1) % 3, cb ^ 1);
        }

        // ---- MFMA chunk c: klo0 from prefetched bvp regs, klo1 loads issued here ----
        {
            const char* xbase = (const char*)&xsb[cb][0];
            const unsigned short* wb1 = Wq +
                ((size_t)(m * NGN + nb16) * NGK + lc * 2 + 1) * 512 + lane * 8;
            short8v bv1[3];
            #pragma unroll
            for (int ni = 0; ni < 3; ++ni)
                bv1[ni] = *(const short8v*)(wb1 + (size_t)ni * NGK * 512);

            __builtin_amdgcn_s_setprio(1);
            #pragma unroll
            for (int mi = 0; mi < 4; ++mi) {
                short8v av = *(const short8v*)(xbase + (mi * 16 + l15) * 128 +
                                               ((lhi * 16) ^ xorv));
                #pragma unroll
                for (int ni = 0; ni < 3; ++ni)
                    acc[mi][ni] = __builtin_amdgcn_mfma_f32_16x16x32_bf16(av, bvp[ni], acc[mi][ni], 0, 0, 0);
            }
            #pragma unroll
            for (int mi = 0; mi < 4; ++mi) {
                short8v av = *(const short8v*)(xbase + (mi * 16 + l15) * 128 +
                                               ((64 + lhi * 16) ^ xorv));
                #pragma unroll
                for (int ni = 0; ni < 3; ++ni)
                    acc[mi][ni] = __builtin_amdgcn_mfma_f32_16x16x32_bf16(av, bv1[ni], acc[mi][ni], 0, 0, 0);
            }
            __builtin_amdgcn_s_setprio(0);
        }

        // ---- prefetch next chunk's klo0 B-frags, then stage chunk c+3 ----
        if (c + 1 < 2 * NCHM) BVP(c + 1);
        if (c + 3 < 2 * NCHM) STAGE(c + 3, c % 3);

        if (lc == NCHM - 1) {
            // ---- epilogue for model m: tanh + 2-col projection ----
            const float* bd = m ? bda : bdb;
            const float* wp = m ? wpa : wpb;
            float bdv[3], w0v[3], w1v[3];
            #pragma unroll
            for (int ni = 0; ni < 3; ++ni) {
                int n = nh * 384 + wid * 48 + ni * 16 + l15;
                bdv[ni] = bd[n];
                w0v[ni] = wp[n];
                w1v[ni] = wp[D + n];
            }
            float ps[4][4][2] = {};
            #pragma unroll
            for (int mi = 0; mi < 4; ++mi)
                #pragma unroll
                for (int ni = 0; ni < 3; ++ni)
                    #pragma unroll
                    for (int r = 0; r < 4; ++r) {
                        float t = fast_tanh(acc[mi][ni][r] + bdv[ni]);
                        ps[mi][r][0] += t * w0v[ni];
                        ps[mi][r][1] += t * w1v[ni];
                    }
            #pragma unroll
            for (int mi = 0; mi < 4; ++mi)
                #pragma unroll
                for (int r = 0; r < 4; ++r)
                    #pragma unroll
                    for (int cc = 0; cc < 2; ++cc) {
                        float v = ps[mi][r][cc];
                        v += __shfl_xor(v, 1);
                        v += __shfl_xor(v, 2);
                        v += __shfl_xor(v, 4);
                        v += __shfl_xor(v, 8);
                        ps[mi][r][cc] = v;
                    }
            if (l15 == 0) {
                #pragma unroll
                for (int mi = 0; mi < 4; ++mi)
                    #pragma unroll
                    for (int r = 0; r < 4; ++r) {
                        int row = mi * 16 + lhi * 4 + r;
                        outp[wid][row][0] = ps[mi][r][0];
                        outp[wid][row][1] = ps[mi][r][1];
                    }
            }
            BAR();                                       // orders outp and serves as chunk barrier
            if (tid < 128) {
                int row = tid >> 1, cc = tid & 1;
                float s = 0.0f;
                #pragma unroll
                for (int w = 0; w < 8; ++w) s += outp[w][row][cc];
                outv += s;
            }
            #pragma unroll
            for (int mi = 0; mi < 4; ++mi)
                #pragma unroll
                for (int ni = 0; ni < 3; ++ni)
                    acc[mi][ni] = (f32x4){0.f, 0.f, 0.f, 0.f};
        } else {
            BAR();
        }
    }
    #undef STAGE
    #undef CVTL
    #undef BVP
    #undef BAR

    // ---- write this block's partial (per n-half) ----
    if (tid < 128) {
        int row = tid >> 1, cc = tid & 1;
        size_t R = (size_t)mtile * BM + row;
        pws[((size_t)nh * Brows + R) * 2 + cc] = outv;
    }
}

// ---------------- combine: n-half partials + gather + biases ----------------
__global__ void k_combine(const float* __restrict__ pws, const int* __restrict__ pairs,
                          const float* __restrict__ T1b, const float* __restrict__ T2b,
                          const float* __restrict__ Ta,
                          const float* __restrict__ bpb, const float* __restrict__ bpa,
                          const float* __restrict__ b1b, const float* __restrict__ b2b,
                          const float* __restrict__ b1a, const float* __restrict__ b2a,
                          float* __restrict__ out, int B) {
    int r = blockIdx.x * blockDim.x + threadIdx.x;
    if (r >= B) return;
    const int* pr = pairs + (size_t)r * 3;
    int i0 = pr[0], j = pr[1], k2 = pr[2];
    #pragma unroll
    for (int c = 0; c < 2; ++c) {
        float g = T1b[((size_t)i0 * NS + j) * 2 + c]
                + T2b[((size_t)i0 * NS + k2) * 2 + c]
                + Ta[((size_t)i0 * NS + j) * 2 + c];
        float bias = bpb[c] + bpa[c] + b1b[c] + b2b[c] + b1a[c] + b2a[c];
        out[(size_t)r * 2 + c] = pws[(size_t)r * 2 + c] + pws[((size_t)B + r) * 2 + c] + g + bias;
    }
}

extern "C" void kernel_launch(void* const* d_in, const int* in_sizes, int n_in,
                              void* d_out, int out_size, void* d_ws, size_t ws_size,
                              hipStream_t stream) {
    const float* xb   = (const float*)d_in[0];
    const float* db   = (const float*)d_in[1];
    const int*   pairs= (const int*)d_in[2];
    const float* xa   = (const float*)d_in[3];
    const float* da   = (const float*)d_in[4];
    const float* Wdb  = (const float*)d_in[5];
    const float* bdb  = (const float*)d_in[6];
    const float* Wda  = (const float*)d_in[7];
    const float* bda  = (const float*)d_in[8];
    const float* Wpb  = (const float*)d_in[9];
    const float* bpb  = (const float*)d_in[10];
    const float* Wpa  = (const float*)d_in[11];
    const float* bpa  = (const float*)d_in[12];
    const float* W1b  = (const float*)d_in[13];
    const float* b1b  = (const float*)d_in[14];
    const float* W2b  = (const float*)d_in[15];
    const float* b2b  = (const float*)d_in[16];
    const float* W1a  = (const float*)d_in[17];
    const float* b1a  = (const float*)d_in[18];
    const float* W2a  = (const float*)d_in[19];
    const float* b2a  = (const float*)d_in[20];
    float* out = (float*)d_out;

    const int B = in_sizes[0] / D;                       // 65536

    char* ws = (char*)d_ws;
    int* flags = (int*)ws;                               // 2048 B
    unsigned short* Wq = (unsigned short*)(ws + 2048);   // 2,359,296 B
    float* T1b = (float*)(ws + 2048 + 2359296);
    float* T2b = T1b + NTAB * NS * 2;
    float* Ta  = T2b + NTAB * NS * 2;
    float* pws = Ta + NTAB * NS * 2;                     // 2*B*2 floats

    hipMemsetAsync(flags, 0, NTAB * sizeof(int), stream);
    k_scan_pairs<<<(B + 255) / 256, 256, 0, stream>>>(pairs, flags, B);
    const int conv_blocks = (2 * NGN * NGK + 3) / 4;     // 576
    k_tables_convq<<<NTAB * 4 + conv_blocks, 256, 0, stream>>>(
        db, da, W1b, W2b, W1a, W2a, flags, T1b, T2b, Ta, Wdb, Wda, Wq);
    k_main<<<(B / BM) * 2, 512, 0, stream>>>(xb, xa, Wq, bdb, bda, Wpb, Wpa, pws, B);
    k_combine<<<(B + 255) / 256, 256, 0, stream>>>(pws, pairs, T1b, T2b, Ta,
                                                   bpb, bpa, b1b, b2b, b1a, b2a, out, B);
}